// Round 2
// baseline (413.838 us; speedup 1.0000x reference)
//
#include <hip/hip_runtime.h>

// AdaConv2d: out[b,c,h,w] = sum_{ki,kj} xpad[b,c,h+ki-1,w+kj-1] * dk[b,c,ki*3+kj,h,w]
// Shapes: x [8,64,128,128] f32, dk [8,64,9,128,128] f32, out [8,64,128,128] f32.
// Memory-bound: dk (302 MB) read-once dominates. Each thread -> 4 consecutive
// pixels, float4 everywhere. x neighborhood via L1/L2 (64 KB/plane, high reuse).

constexpr int Bc = 8, Cc = 64, Hc = 128, Wc = 128;
constexpr int HW = Hc * Wc;

__global__ __launch_bounds__(256) void adaconv2d_kernel(
    const float* __restrict__ x,
    const float* __restrict__ dk,
    float* __restrict__ out)
{
    // total quads = B*C*H*(W/4) = 2,097,152 ; grid covers exactly
    int tid = blockIdx.x * blockDim.x + threadIdx.x;
    int w0   = (tid & 31) << 2;   // 0,4,...,124
    int rest = tid >> 5;
    int h    = rest & (Hc - 1);
    int bc   = rest >> 7;         // 0..511 (b*C + c)

    const float* xp = x + bc * HW;
    const float* kp = dk + (long long)bc * 9 * HW + h * Wc + w0;

    // x rows h-1,h,h+1, columns w0-1 .. w0+4  (zero-padded at borders)
    float xr[3][6];
    #pragma unroll
    for (int r = 0; r < 3; ++r) {
        int hh = h + r - 1;
        if (hh >= 0 && hh < Hc) {
            const float* row = xp + hh * Wc;
            float4 m = *reinterpret_cast<const float4*>(row + w0);
            xr[r][1] = m.x; xr[r][2] = m.y; xr[r][3] = m.z; xr[r][4] = m.w;
            xr[r][0] = (w0 > 0)        ? row[w0 - 1] : 0.f;
            xr[r][5] = (w0 + 4 < Wc)   ? row[w0 + 4] : 0.f;
        } else {
            #pragma unroll
            for (int j = 0; j < 6; ++j) xr[r][j] = 0.f;
        }
    }

    float4 acc = make_float4(0.f, 0.f, 0.f, 0.f);
    #pragma unroll
    for (int r = 0; r < 3; ++r) {
        #pragma unroll
        for (int s = 0; s < 3; ++s) {
            float4 k = *reinterpret_cast<const float4*>(kp + (r * 3 + s) * HW);
            // out col w0+j uses x col w0+j+s-1 == xr[r][j+s]
            acc.x += xr[r][s + 0] * k.x;
            acc.y += xr[r][s + 1] * k.y;
            acc.z += xr[r][s + 2] * k.z;
            acc.w += xr[r][s + 3] * k.w;
        }
    }

    *reinterpret_cast<float4*>(out + bc * HW + h * Wc + w0) = acc;
}

extern "C" void kernel_launch(void* const* d_in, const int* in_sizes, int n_in,
                              void* d_out, int out_size, void* d_ws, size_t ws_size,
                              hipStream_t stream) {
    const float* x  = (const float*)d_in[0];
    const float* dk = (const float*)d_in[1];
    float* out      = (float*)d_out;

    const int total_quads = Bc * Cc * Hc * (Wc / 4); // 2,097,152
    const int block = 256;
    const int grid  = total_quads / block;           // 8192
    adaconv2d_kernel<<<grid, block, 0, stream>>>(x, dk, out);
}